// Round 5
// baseline (4329.125 us; speedup 1.0000x reference)
//
#include <hip/hip_runtime.h>

// Chamfer distance, B=16, N=M=4096, D=3.
// dist(i,j) = n1 + n2 - 2*x1.x2 as ONE bf16 MFMA per 32x32 tile (norms folded
// into padded K slots, hi/lo bf16 split => exact-grade; absmax 0.0 since R1).
// R5: anti-spill rebuild. R4's loop had ~168 live VGPRs vs the 128 cap from
// launch_bounds(256,4) -> scratch spills in the hot loop (theory for the ~30us
// main). Now: only 2 MFMA results concurrent, modulo-4 in-place buffers (no
// ring-shift movs), full unroll (static addr immediates), peak ~114 VGPR.
// Quarter-column slices: wave = 64 rows x 32 col-tiles, 8192 waves; each
// slice = 64 KB of prepacked fragments, its 16 blocks pinned to one XCD.

typedef __attribute__((ext_vector_type(8))) __bf16 bf16x8;
typedef __attribute__((ext_vector_type(16))) float f32x16;

#define PTS 4096
#define TILES 128  // PTS/32
#define NB 16

__device__ __forceinline__ unsigned f2bf(float f) {
  unsigned u = __float_as_uint(f);
  return (u + 0x7FFFu + ((u >> 16) & 1u)) >> 16;  // RNE bf16 bits
}
__device__ __forceinline__ float bf2f(unsigned s) {
  return __uint_as_float(s << 16);
}
__device__ __forceinline__ unsigned pk(unsigned lo, unsigned hi) {
  return (lo & 0xFFFFu) | (hi << 16);
}

// ---- prepack B-side fragments + init rowm ----
// Bfr[(((d*NB+b)*TILES+t)*2+h)*32 + l31]
// B k-vec: w0=[Hx Hy Hz Lx Ly Lz Hx Hy]  w1=[Hz nh nl 1 1 0 0 0], H,L split -2q.
__global__ __launch_bounds__(256) void prepack_b(const float* __restrict__ x1,
                                                 const float* __restrict__ x2,
                                                 uint4* __restrict__ Bfr,
                                                 unsigned* __restrict__ rowm) {
  const int id = blockIdx.x * 256 + threadIdx.x;  // 2*NB*PTS = 131072
  rowm[id] = 0x7F800000u;                         // +inf (all dists >= 0)
  const int d = id >> 16;
  const int b = (id >> 12) & (NB - 1);
  const int j = id & (PTS - 1);
  const float* q = (d ? x1 : x2) + (size_t)(b * PTS + j) * 3;
  const float x = q[0], y = q[1], z = q[2];
  const float sx = -2.f * x, sy = -2.f * y, sz = -2.f * z;
  const unsigned Hx = f2bf(sx), Hy = f2bf(sy), Hz = f2bf(sz);
  const unsigned Lx = f2bf(sx - bf2f(Hx));
  const unsigned Ly = f2bf(sy - bf2f(Hy));
  const unsigned Lz = f2bf(sz - bf2f(Hz));
  const float n = fmaf(x, x, fmaf(y, y, z * z));
  const unsigned nh = f2bf(n), nl = f2bf(n - bf2f(nh));
  const unsigned one = 0x3F80u;
  uint4 w0, w1;
  w0.x = pk(Hx, Hy); w0.y = pk(Hz, Lx); w0.z = pk(Ly, Lz); w0.w = pk(Hx, Hy);
  w1.x = pk(Hz, nh); w1.y = pk(nl, one); w1.z = pk(one, 0u); w1.w = 0u;
  uint4* base =
      Bfr + ((size_t)((d * NB + b) * TILES + (j >> 5)) * 2) * 32 + (j & 31);
  base[0]  = w0;   // half 0
  base[32] = w1;   // half 1
}

// ---- main: 256 threads = 4 waves sharing one row-group (256 rows) and one
// quarter-column stream (32 tiles, 64 KB, XCD-L2 resident). No LDS/barriers.
__global__ __launch_bounds__(256, 4) void chamfer_main(
    const float* __restrict__ x1, const float* __restrict__ x2,
    const uint4* __restrict__ Bfr, unsigned* __restrict__ rowm) {
  const int s  = blockIdx.x;           // 128 slices: (dir, batch, quarter)
  const int d  = s & 1;
  const int b  = (s >> 1) & (NB - 1);
  const int qq = (s >> 5) & 3;         // column quarter
  const int rg = blockIdx.y;           // 16 row-groups of 256 rows

  const int tid  = threadIdx.x;
  const int lane = tid & 63;
  const int half = lane >> 5;          // K-half this lane supplies to MFMA
  const int l31  = lane & 31;
  const int wave = tid >> 6;

  // --- build A fragments from raw points (row tiles t0, t0+1) ---
  // A k-vec: w0=[hx hy hz hx hy hz lx ly]  w1=[lz 1 1 nh nl 0 0 0]
  const float* P = d ? x2 : x1;
  const int t0 = rg * 8 + wave * 2;
  bf16x8 af[2];
#pragma unroll
  for (int rr = 0; rr < 2; ++rr) {
    const int r = (t0 + rr) * 32 + l31;
    const float* p = P + (size_t)(b * PTS + r) * 3;
    const float x = p[0], y = p[1], zc = p[2];
    const unsigned hx = f2bf(x), hy = f2bf(y), hz = f2bf(zc);
    const unsigned lx = f2bf(x - bf2f(hx));
    const unsigned ly = f2bf(y - bf2f(hy));
    const unsigned lz = f2bf(zc - bf2f(hz));
    const float n = fmaf(x, x, fmaf(y, y, zc * zc));
    const unsigned nh = f2bf(n), nl = f2bf(n - bf2f(nh));
    const unsigned one = 0x3F80u;
    uint4 w0, w1;
    w0.x = pk(hx, hy); w0.y = pk(hz, hx); w0.z = pk(hy, hz); w0.w = pk(lx, ly);
    w1.x = pk(lz, one); w1.y = pk(one, nh); w1.z = pk(nl, 0u); w1.w = 0u;
    uint4 w;
    w.x = half ? w1.x : w0.x; w.y = half ? w1.y : w0.y;
    w.z = half ? w1.z : w0.z; w.w = half ? w1.w : w0.w;
    af[rr] = *(const bf16x8*)&w;
  }
  const bf16x8 af0 = af[0], af1 = af[1];

  f32x16 zero;
#pragma unroll
  for (int e = 0; e < 16; ++e) zero[e] = 0.f;

  float rm0[16], rm1[16];
#pragma unroll
  for (int e = 0; e < 16; ++e) { rm0[e] = 3.0e38f; rm1[e] = 3.0e38f; }

  // --- stream this quarter's 32 tiles; 4 in-place buffers, loads 2-6 ahead ---
  const uint4* bp =
      Bfr + ((size_t)((d * NB + b) * TILES + qq * 32) * 2) * 32;
  const int off = half * 32 + l31;  // within a tile: h*32 + col
  bf16x8 q0 = *(const bf16x8*)&bp[0 * 64 + off];
  bf16x8 q1 = *(const bf16x8*)&bp[1 * 64 + off];
  bf16x8 q2 = *(const bf16x8*)&bp[2 * 64 + off];
  bf16x8 q3 = *(const bf16x8*)&bp[3 * 64 + off];

#pragma unroll
  for (int t = 0; t < 32; t += 4) {
    // consume q0,q1 (2 results concurrent max), refill in place 4 ahead
    {
      const f32x16 a0 =
          __builtin_amdgcn_mfma_f32_32x32x16_bf16(af0, q0, zero, 0, 0, 0);
      const f32x16 a1 =
          __builtin_amdgcn_mfma_f32_32x32x16_bf16(af0, q1, zero, 0, 0, 0);
#pragma unroll
      for (int e = 0; e < 16; ++e)
        rm0[e] = fminf(fminf(a0[e], a1[e]), rm0[e]);  // v_min3_f32
      const f32x16 a2 =
          __builtin_amdgcn_mfma_f32_32x32x16_bf16(af1, q0, zero, 0, 0, 0);
      const f32x16 a3 =
          __builtin_amdgcn_mfma_f32_32x32x16_bf16(af1, q1, zero, 0, 0, 0);
#pragma unroll
      for (int e = 0; e < 16; ++e)
        rm1[e] = fminf(fminf(a2[e], a3[e]), rm1[e]);
    }
    q0 = *(const bf16x8*)&bp[(((t + 4) & 31)) * 64 + off];
    q1 = *(const bf16x8*)&bp[(((t + 5) & 31)) * 64 + off];
    {
      const f32x16 a0 =
          __builtin_amdgcn_mfma_f32_32x32x16_bf16(af0, q2, zero, 0, 0, 0);
      const f32x16 a1 =
          __builtin_amdgcn_mfma_f32_32x32x16_bf16(af0, q3, zero, 0, 0, 0);
#pragma unroll
      for (int e = 0; e < 16; ++e)
        rm0[e] = fminf(fminf(a0[e], a1[e]), rm0[e]);
      const f32x16 a2 =
          __builtin_amdgcn_mfma_f32_32x32x16_bf16(af1, q2, zero, 0, 0, 0);
      const f32x16 a3 =
          __builtin_amdgcn_mfma_f32_32x32x16_bf16(af1, q3, zero, 0, 0, 0);
#pragma unroll
      for (int e = 0; e < 16; ++e)
        rm1[e] = fminf(fminf(a2[e], a3[e]), rm1[e]);
    }
    q2 = *(const bf16x8*)&bp[(((t + 6) & 31)) * 64 + off];
    q3 = *(const bf16x8*)&bp[(((t + 7) & 31)) * 64 + off];
  }

  // --- per-row min over this wave's 32 cols-per-half, then uint atomicMin ---
  // C/D layout: col = lane&31, row_local = (e&3) + 8*(e>>2) + 4*half.
  unsigned* rbase = rowm + (size_t)(d * NB + b) * PTS + t0 * 32;
#pragma unroll
  for (int e = 0; e < 16; ++e) {
    float v = rm0[e];
    v = fminf(v, __shfl_xor(v, 1));
    v = fminf(v, __shfl_xor(v, 2));
    v = fminf(v, __shfl_xor(v, 4));
    v = fminf(v, __shfl_xor(v, 8));
    v = fminf(v, __shfl_xor(v, 16));
    if (l31 == e) {
      const int rl = (e & 3) + 8 * (e >> 2) + 4 * half;
      atomicMin(rbase + rl, __float_as_uint(fmaxf(v, 0.f)));
    }
  }
#pragma unroll
  for (int e = 0; e < 16; ++e) {
    float v = rm1[e];
    v = fminf(v, __shfl_xor(v, 1));
    v = fminf(v, __shfl_xor(v, 2));
    v = fminf(v, __shfl_xor(v, 4));
    v = fminf(v, __shfl_xor(v, 8));
    v = fminf(v, __shfl_xor(v, 16));
    if (l31 == e) {
      const int rl = 32 + (e & 3) + 8 * (e >> 2) + 4 * half;
      atomicMin(rbase + rl, __float_as_uint(fmaxf(v, 0.f)));
    }
  }
}

// ---- reduce: out[b] = mean(rowmin d=0) + mean(rowmin d=1) ----
__global__ __launch_bounds__(256) void reduce_rows(
    const unsigned* __restrict__ rowm, float* __restrict__ out) {
  const int b = blockIdx.x;
  const int tid = threadIdx.x;
  const unsigned* r0 = rowm + (size_t)b * PTS;
  const unsigned* r1 = rowm + (size_t)(NB + b) * PTS;
  float s = 0.f;
  for (int i = tid; i < PTS; i += 256)
    s += __uint_as_float(r0[i]) + __uint_as_float(r1[i]);
  s += __shfl_xor(s, 1);
  s += __shfl_xor(s, 2);
  s += __shfl_xor(s, 4);
  s += __shfl_xor(s, 8);
  s += __shfl_xor(s, 16);
  s += __shfl_xor(s, 32);
  __shared__ float acc[4];
  if ((tid & 63) == 0) acc[tid >> 6] = s;
  __syncthreads();
  if (tid == 0) out[b] = (acc[0] + acc[1] + acc[2] + acc[3]) * (1.f / PTS);
}

extern "C" void kernel_launch(void* const* d_in, const int* in_sizes, int n_in,
                              void* d_out, int out_size, void* d_ws,
                              size_t ws_size, hipStream_t stream) {
  const float* x1 = (const float*)d_in[0];
  const float* x2 = (const float*)d_in[1];
  float* out = (float*)d_out;

  uint4* Bfr = (uint4*)d_ws;  // 2*NB*TILES*2*32 uint4 = 4 MB
  unsigned* rowm =
      (unsigned*)((char*)d_ws + (size_t)2 * NB * TILES * 2 * 32 * 16);

  prepack_b<<<(2 * NB * PTS) / 256, 256, 0, stream>>>(x1, x2, Bfr, rowm);
  dim3 grid(128, NB);  // x = (dir,b,quarter) slice -> XCD = x%8 ; y = row-group
  chamfer_main<<<grid, 256, 0, stream>>>(x1, x2, Bfr, rowm);
  reduce_rows<<<NB, 256, 0, stream>>>(rowm, out);
}

// Round 6
// 4229.455 us; speedup vs baseline: 1.0236x; 1.0236x over previous
//
#include <hip/hip_runtime.h>

// Chamfer distance, B=16, N=M=4096, D=3.
// dist(i,j) = n1 + n2 - 2*x1.x2 as ONE bf16 MFMA per 32x32 tile (norms folded
// into padded K slots, hi/lo bf16 split => exact-grade; absmax 0.0 since R1).
// R6: R5 structure, spill fix. R5's launch_bounds(256,4) gave a 128-reg
// unified budget (64 VGPR + 64 AGPR per CSV) vs ~135 live -> scratch spills
// (17 GB HBM traffic on a 4 MB input!). (256,3) -> 168-reg budget, live set
// fits, zero spill. 12 waves/CU x 4 loads in flight still >> Little's-law
// requirement for the L2 stream.

typedef __attribute__((ext_vector_type(8))) __bf16 bf16x8;
typedef __attribute__((ext_vector_type(16))) float f32x16;

#define PTS 4096
#define TILES 128  // PTS/32
#define NB 16

__device__ __forceinline__ unsigned f2bf(float f) {
  unsigned u = __float_as_uint(f);
  return (u + 0x7FFFu + ((u >> 16) & 1u)) >> 16;  // RNE bf16 bits
}
__device__ __forceinline__ float bf2f(unsigned s) {
  return __uint_as_float(s << 16);
}
__device__ __forceinline__ unsigned pk(unsigned lo, unsigned hi) {
  return (lo & 0xFFFFu) | (hi << 16);
}

// ---- prepack B-side fragments + init rowm ----
// Bfr[(((d*NB+b)*TILES+t)*2+h)*32 + l31]
// B k-vec: w0=[Hx Hy Hz Lx Ly Lz Hx Hy]  w1=[Hz nh nl 1 1 0 0 0], H,L split -2q.
__global__ __launch_bounds__(256) void prepack_b(const float* __restrict__ x1,
                                                 const float* __restrict__ x2,
                                                 uint4* __restrict__ Bfr,
                                                 unsigned* __restrict__ rowm) {
  const int id = blockIdx.x * 256 + threadIdx.x;  // 2*NB*PTS = 131072
  rowm[id] = 0x7F800000u;                         // +inf (all dists >= 0)
  const int d = id >> 16;
  const int b = (id >> 12) & (NB - 1);
  const int j = id & (PTS - 1);
  const float* q = (d ? x1 : x2) + (size_t)(b * PTS + j) * 3;
  const float x = q[0], y = q[1], z = q[2];
  const float sx = -2.f * x, sy = -2.f * y, sz = -2.f * z;
  const unsigned Hx = f2bf(sx), Hy = f2bf(sy), Hz = f2bf(sz);
  const unsigned Lx = f2bf(sx - bf2f(Hx));
  const unsigned Ly = f2bf(sy - bf2f(Hy));
  const unsigned Lz = f2bf(sz - bf2f(Hz));
  const float n = fmaf(x, x, fmaf(y, y, z * z));
  const unsigned nh = f2bf(n), nl = f2bf(n - bf2f(nh));
  const unsigned one = 0x3F80u;
  uint4 w0, w1;
  w0.x = pk(Hx, Hy); w0.y = pk(Hz, Lx); w0.z = pk(Ly, Lz); w0.w = pk(Hx, Hy);
  w1.x = pk(Hz, nh); w1.y = pk(nl, one); w1.z = pk(one, 0u); w1.w = 0u;
  uint4* base =
      Bfr + ((size_t)((d * NB + b) * TILES + (j >> 5)) * 2) * 32 + (j & 31);
  base[0]  = w0;   // half 0
  base[32] = w1;   // half 1
}

// ---- main: 256 threads = 4 waves sharing one row-group (256 rows) and one
// quarter-column stream (32 tiles, 64 KB, XCD-L2 resident). No LDS/barriers.
__global__ __launch_bounds__(256, 3) void chamfer_main(
    const float* __restrict__ x1, const float* __restrict__ x2,
    const uint4* __restrict__ Bfr, unsigned* __restrict__ rowm) {
  const int s  = blockIdx.x;           // 128 slices: (dir, batch, quarter)
  const int d  = s & 1;
  const int b  = (s >> 1) & (NB - 1);
  const int qq = (s >> 5) & 3;         // column quarter
  const int rg = blockIdx.y;           // 16 row-groups of 256 rows

  const int tid  = threadIdx.x;
  const int lane = tid & 63;
  const int half = lane >> 5;          // K-half this lane supplies to MFMA
  const int l31  = lane & 31;
  const int wave = tid >> 6;

  // --- build A fragments from raw points (row tiles t0, t0+1) ---
  // A k-vec: w0=[hx hy hz hx hy hz lx ly]  w1=[lz 1 1 nh nl 0 0 0]
  const float* P = d ? x2 : x1;
  const int t0 = rg * 8 + wave * 2;
  bf16x8 af[2];
#pragma unroll
  for (int rr = 0; rr < 2; ++rr) {
    const int r = (t0 + rr) * 32 + l31;
    const float* p = P + (size_t)(b * PTS + r) * 3;
    const float x = p[0], y = p[1], zc = p[2];
    const unsigned hx = f2bf(x), hy = f2bf(y), hz = f2bf(zc);
    const unsigned lx = f2bf(x - bf2f(hx));
    const unsigned ly = f2bf(y - bf2f(hy));
    const unsigned lz = f2bf(zc - bf2f(hz));
    const float n = fmaf(x, x, fmaf(y, y, zc * zc));
    const unsigned nh = f2bf(n), nl = f2bf(n - bf2f(nh));
    const unsigned one = 0x3F80u;
    uint4 w0, w1;
    w0.x = pk(hx, hy); w0.y = pk(hz, hx); w0.z = pk(hy, hz); w0.w = pk(lx, ly);
    w1.x = pk(lz, one); w1.y = pk(one, nh); w1.z = pk(nl, 0u); w1.w = 0u;
    uint4 w;
    w.x = half ? w1.x : w0.x; w.y = half ? w1.y : w0.y;
    w.z = half ? w1.z : w0.z; w.w = half ? w1.w : w0.w;
    af[rr] = *(const bf16x8*)&w;
  }
  const bf16x8 af0 = af[0], af1 = af[1];

  f32x16 zero;
#pragma unroll
  for (int e = 0; e < 16; ++e) zero[e] = 0.f;

  float rm0[16], rm1[16];
#pragma unroll
  for (int e = 0; e < 16; ++e) { rm0[e] = 3.0e38f; rm1[e] = 3.0e38f; }

  // --- stream this quarter's 32 tiles; 4 in-place buffers, loads 2-6 ahead ---
  const uint4* bp =
      Bfr + ((size_t)((d * NB + b) * TILES + qq * 32) * 2) * 32;
  const int off = half * 32 + l31;  // within a tile: h*32 + col
  bf16x8 q0 = *(const bf16x8*)&bp[0 * 64 + off];
  bf16x8 q1 = *(const bf16x8*)&bp[1 * 64 + off];
  bf16x8 q2 = *(const bf16x8*)&bp[2 * 64 + off];
  bf16x8 q3 = *(const bf16x8*)&bp[3 * 64 + off];

#pragma unroll
  for (int t = 0; t < 32; t += 4) {
    // consume q0,q1 (2 results concurrent max), refill in place 4 ahead
    {
      const f32x16 a0 =
          __builtin_amdgcn_mfma_f32_32x32x16_bf16(af0, q0, zero, 0, 0, 0);
      const f32x16 a1 =
          __builtin_amdgcn_mfma_f32_32x32x16_bf16(af0, q1, zero, 0, 0, 0);
#pragma unroll
      for (int e = 0; e < 16; ++e)
        rm0[e] = fminf(fminf(a0[e], a1[e]), rm0[e]);  // v_min3_f32
      const f32x16 a2 =
          __builtin_amdgcn_mfma_f32_32x32x16_bf16(af1, q0, zero, 0, 0, 0);
      const f32x16 a3 =
          __builtin_amdgcn_mfma_f32_32x32x16_bf16(af1, q1, zero, 0, 0, 0);
#pragma unroll
      for (int e = 0; e < 16; ++e)
        rm1[e] = fminf(fminf(a2[e], a3[e]), rm1[e]);
    }
    q0 = *(const bf16x8*)&bp[(((t + 4) & 31)) * 64 + off];
    q1 = *(const bf16x8*)&bp[(((t + 5) & 31)) * 64 + off];
    {
      const f32x16 a0 =
          __builtin_amdgcn_mfma_f32_32x32x16_bf16(af0, q2, zero, 0, 0, 0);
      const f32x16 a1 =
          __builtin_amdgcn_mfma_f32_32x32x16_bf16(af0, q3, zero, 0, 0, 0);
#pragma unroll
      for (int e = 0; e < 16; ++e)
        rm0[e] = fminf(fminf(a0[e], a1[e]), rm0[e]);
      const f32x16 a2 =
          __builtin_amdgcn_mfma_f32_32x32x16_bf16(af1, q2, zero, 0, 0, 0);
      const f32x16 a3 =
          __builtin_amdgcn_mfma_f32_32x32x16_bf16(af1, q3, zero, 0, 0, 0);
#pragma unroll
      for (int e = 0; e < 16; ++e)
        rm1[e] = fminf(fminf(a2[e], a3[e]), rm1[e]);
    }
    q2 = *(const bf16x8*)&bp[(((t + 6) & 31)) * 64 + off];
    q3 = *(const bf16x8*)&bp[(((t + 7) & 31)) * 64 + off];
  }

  // --- per-row min over this wave's 32 cols-per-half, then uint atomicMin ---
  // C/D layout: col = lane&31, row_local = (e&3) + 8*(e>>2) + 4*half.
  unsigned* rbase = rowm + (size_t)(d * NB + b) * PTS + t0 * 32;
#pragma unroll
  for (int e = 0; e < 16; ++e) {
    float v = rm0[e];
    v = fminf(v, __shfl_xor(v, 1));
    v = fminf(v, __shfl_xor(v, 2));
    v = fminf(v, __shfl_xor(v, 4));
    v = fminf(v, __shfl_xor(v, 8));
    v = fminf(v, __shfl_xor(v, 16));
    if (l31 == e) {
      const int rl = (e & 3) + 8 * (e >> 2) + 4 * half;
      atomicMin(rbase + rl, __float_as_uint(fmaxf(v, 0.f)));
    }
  }
#pragma unroll
  for (int e = 0; e < 16; ++e) {
    float v = rm1[e];
    v = fminf(v, __shfl_xor(v, 1));
    v = fminf(v, __shfl_xor(v, 2));
    v = fminf(v, __shfl_xor(v, 4));
    v = fminf(v, __shfl_xor(v, 8));
    v = fminf(v, __shfl_xor(v, 16));
    if (l31 == e) {
      const int rl = 32 + (e & 3) + 8 * (e >> 2) + 4 * half;
      atomicMin(rbase + rl, __float_as_uint(fmaxf(v, 0.f)));
    }
  }
}

// ---- reduce: out[b] = mean(rowmin d=0) + mean(rowmin d=1) ----
__global__ __launch_bounds__(256) void reduce_rows(
    const unsigned* __restrict__ rowm, float* __restrict__ out) {
  const int b = blockIdx.x;
  const int tid = threadIdx.x;
  const unsigned* r0 = rowm + (size_t)b * PTS;
  const unsigned* r1 = rowm + (size_t)(NB + b) * PTS;
  float s = 0.f;
  for (int i = tid; i < PTS; i += 256)
    s += __uint_as_float(r0[i]) + __uint_as_float(r1[i]);
  s += __shfl_xor(s, 1);
  s += __shfl_xor(s, 2);
  s += __shfl_xor(s, 4);
  s += __shfl_xor(s, 8);
  s += __shfl_xor(s, 16);
  s += __shfl_xor(s, 32);
  __shared__ float acc[4];
  if ((tid & 63) == 0) acc[tid >> 6] = s;
  __syncthreads();
  if (tid == 0) out[b] = (acc[0] + acc[1] + acc[2] + acc[3]) * (1.f / PTS);
}

extern "C" void kernel_launch(void* const* d_in, const int* in_sizes, int n_in,
                              void* d_out, int out_size, void* d_ws,
                              size_t ws_size, hipStream_t stream) {
  const float* x1 = (const float*)d_in[0];
  const float* x2 = (const float*)d_in[1];
  float* out = (float*)d_out;

  uint4* Bfr = (uint4*)d_ws;  // 2*NB*TILES*2*32 uint4 = 4 MB
  unsigned* rowm =
      (unsigned*)((char*)d_ws + (size_t)2 * NB * TILES * 2 * 32 * 16);

  prepack_b<<<(2 * NB * PTS) / 256, 256, 0, stream>>>(x1, x2, Bfr, rowm);
  dim3 grid(128, NB);  // x = (dir,b,quarter) slice -> XCD = x%8 ; y = row-group
  chamfer_main<<<grid, 256, 0, stream>>>(x1, x2, Bfr, rowm);
  reduce_rows<<<NB, 256, 0, stream>>>(rowm, out);
}

// Round 7
// 134.537 us; speedup vs baseline: 32.1778x; 31.4370x over previous
//
#include <hip/hip_runtime.h>

// Chamfer distance, B=16, N=M=4096, D=3.
// dist(i,j) = n1 + n2 - 2*x1.x2 as ONE bf16 MFMA per 32x32 tile (norms folded
// into padded K slots, hi/lo bf16 split => exact-grade; absmax 0.0 since R1).
// R7: anti-spill by construction. R5/R6's 2-row-tile + paired-min3 structure
// kept ~130+ values live -> scratch thrash (17 GB HBM traffic) at ANY budget
// tried. Now: 1 row-tile/wave, ONE MFMA result live, single rm[16], 4-deep
// in-place ring => ~96 live regs. Wave spans ALL 4096 cols => full row-min
// in-wave, butterfly, one atomicAdd per wave: rowm buffer, atomicMin, and the
// reduce kernel are deleted. 1024 blocks = exactly 4 blocks/CU, one round.

typedef __attribute__((ext_vector_type(8))) __bf16 bf16x8;
typedef __attribute__((ext_vector_type(16))) float f32x16;

#define PTS 4096
#define TILES 128  // PTS/32
#define NB 16

__device__ __forceinline__ unsigned f2bf(float f) {
  unsigned u = __float_as_uint(f);
  return (u + 0x7FFFu + ((u >> 16) & 1u)) >> 16;  // RNE bf16 bits
}
__device__ __forceinline__ float bf2f(unsigned s) {
  return __uint_as_float(s << 16);
}
__device__ __forceinline__ unsigned pk(unsigned lo, unsigned hi) {
  return (lo & 0xFFFFu) | (hi << 16);
}

// ---- prepack B-side fragments + zero out[] ----
// Bfr[((d*NB+b)*TILES + t)*64 + half*32 + col]   (uint4 units)
// B k-vec: w0=[Hx Hy Hz Lx Ly Lz Hx Hy]  w1=[Hz nh nl 1 1 0 0 0], H,L split -2q.
__global__ __launch_bounds__(256) void prepack_b(const float* __restrict__ x1,
                                                 const float* __restrict__ x2,
                                                 uint4* __restrict__ Bfr,
                                                 float* __restrict__ out) {
  const int id = blockIdx.x * 256 + threadIdx.x;  // 2*NB*PTS = 131072
  if (id < NB) out[id] = 0.f;                     // main accumulates into out
  const int d = id >> 16;
  const int b = (id >> 12) & (NB - 1);
  const int j = id & (PTS - 1);
  const float* q = (d ? x1 : x2) + (size_t)(b * PTS + j) * 3;
  const float x = q[0], y = q[1], z = q[2];
  const float sx = -2.f * x, sy = -2.f * y, sz = -2.f * z;
  const unsigned Hx = f2bf(sx), Hy = f2bf(sy), Hz = f2bf(sz);
  const unsigned Lx = f2bf(sx - bf2f(Hx));
  const unsigned Ly = f2bf(sy - bf2f(Hy));
  const unsigned Lz = f2bf(sz - bf2f(Hz));
  const float n = fmaf(x, x, fmaf(y, y, z * z));
  const unsigned nh = f2bf(n), nl = f2bf(n - bf2f(nh));
  const unsigned one = 0x3F80u;
  uint4 w0, w1;
  w0.x = pk(Hx, Hy); w0.y = pk(Hz, Lx); w0.z = pk(Ly, Lz); w0.w = pk(Hx, Hy);
  w1.x = pk(Hz, nh); w1.y = pk(nl, one); w1.z = pk(one, 0u); w1.w = 0u;
  uint4* base = Bfr + ((size_t)((d * NB + b) * TILES + (j >> 5))) * 64 + (j & 31);
  base[0]  = w0;   // half 0
  base[32] = w1;   // half 1
}

// ---- main: 4 waves/block, wave = 1 row-tile (32 rows) x ALL 128 col-tiles.
// All 4 waves read the identical fragment stream (L1 reuse). No LDS/barriers.
__global__ __launch_bounds__(256, 4) void chamfer_main(
    const float* __restrict__ x1, const float* __restrict__ x2,
    const uint4* __restrict__ Bfr, float* __restrict__ out) {
  const int rg = blockIdx.x;           // 32 row-groups of 128 rows
  const int d  = blockIdx.y >> 4;      // direction
  const int b  = blockIdx.y & (NB - 1);

  const int tid  = threadIdx.x;
  const int lane = tid & 63;
  const int half = lane >> 5;          // K-half this lane supplies to MFMA
  const int l31  = lane & 31;
  const int wave = tid >> 6;

  // --- build A fragment from raw points (row tile t0, row = t0*32 + l31) ---
  // A k-vec: w0=[hx hy hz hx hy hz lx ly]  w1=[lz 1 1 nh nl 0 0 0]
  const float* P = d ? x2 : x1;
  const int t0 = rg * 4 + wave;
  bf16x8 af;
  {
    const int r = t0 * 32 + l31;
    const float* p = P + (size_t)(b * PTS + r) * 3;
    const float x = p[0], y = p[1], zc = p[2];
    const unsigned hx = f2bf(x), hy = f2bf(y), hz = f2bf(zc);
    const unsigned lx = f2bf(x - bf2f(hx));
    const unsigned ly = f2bf(y - bf2f(hy));
    const unsigned lz = f2bf(zc - bf2f(hz));
    const float n = fmaf(x, x, fmaf(y, y, zc * zc));
    const unsigned nh = f2bf(n), nl = f2bf(n - bf2f(nh));
    const unsigned one = 0x3F80u;
    uint4 w0, w1;
    w0.x = pk(hx, hy); w0.y = pk(hz, hx); w0.z = pk(hy, hz); w0.w = pk(lx, ly);
    w1.x = pk(lz, one); w1.y = pk(one, nh); w1.z = pk(nl, 0u); w1.w = 0u;
    uint4 w;
    w.x = half ? w1.x : w0.x; w.y = half ? w1.y : w0.y;
    w.z = half ? w1.z : w0.z; w.w = half ? w1.w : w0.w;
    af = *(const bf16x8*)&w;
  }

  f32x16 zero;
#pragma unroll
  for (int e = 0; e < 16; ++e) zero[e] = 0.f;

  float rm[16];
#pragma unroll
  for (int e = 0; e < 16; ++e) rm[e] = 3.0e38f;

  // --- stream all 128 tiles; 4-buffer in-place ring, loads 4 ahead ---
  const uint4* bp = Bfr + (size_t)((d * NB + b) * TILES) * 64;
  const int off = half * 32 + l31;  // within a tile: half*32 + col
  bf16x8 q0 = *(const bf16x8*)&bp[0 * 64 + off];
  bf16x8 q1 = *(const bf16x8*)&bp[1 * 64 + off];
  bf16x8 q2 = *(const bf16x8*)&bp[2 * 64 + off];
  bf16x8 q3 = *(const bf16x8*)&bp[3 * 64 + off];

  for (int t = 0; t < TILES; t += 4) {
    {
      const f32x16 a =
          __builtin_amdgcn_mfma_f32_32x32x16_bf16(af, q0, zero, 0, 0, 0);
#pragma unroll
      for (int e = 0; e < 16; ++e) rm[e] = fminf(rm[e], a[e]);
      q0 = *(const bf16x8*)&bp[((t + 4) & (TILES - 1)) * 64 + off];
    }
    {
      const f32x16 a =
          __builtin_amdgcn_mfma_f32_32x32x16_bf16(af, q1, zero, 0, 0, 0);
#pragma unroll
      for (int e = 0; e < 16; ++e) rm[e] = fminf(rm[e], a[e]);
      q1 = *(const bf16x8*)&bp[((t + 5) & (TILES - 1)) * 64 + off];
    }
    {
      const f32x16 a =
          __builtin_amdgcn_mfma_f32_32x32x16_bf16(af, q2, zero, 0, 0, 0);
#pragma unroll
      for (int e = 0; e < 16; ++e) rm[e] = fminf(rm[e], a[e]);
      q2 = *(const bf16x8*)&bp[((t + 6) & (TILES - 1)) * 64 + off];
    }
    {
      const f32x16 a =
          __builtin_amdgcn_mfma_f32_32x32x16_bf16(af, q3, zero, 0, 0, 0);
#pragma unroll
      for (int e = 0; e < 16; ++e) rm[e] = fminf(rm[e], a[e]);
      q3 = *(const bf16x8*)&bp[((t + 7) & (TILES - 1)) * 64 + off];
    }
  }

  // --- epilogue: full row mins (butterfly over 32 cols), sum, one atomicAdd.
  // C/D layout: col = lane&31, row_local = (e&3) + 8*(e>>2) + 4*half.
  float ssum = 0.f;
#pragma unroll
  for (int e = 0; e < 16; ++e) {
    float v = rm[e];
    v = fminf(v, __shfl_xor(v, 1));
    v = fminf(v, __shfl_xor(v, 2));
    v = fminf(v, __shfl_xor(v, 4));
    v = fminf(v, __shfl_xor(v, 8));
    v = fminf(v, __shfl_xor(v, 16));
    ssum += v;  // each e is a distinct row of this lane-half
  }
  ssum += __shfl_xor(ssum, 32);  // combine the two 16-row lane halves
  if (lane == 0) atomicAdd(&out[b], ssum * (1.0f / (float)PTS));
}

extern "C" void kernel_launch(void* const* d_in, const int* in_sizes, int n_in,
                              void* d_out, int out_size, void* d_ws,
                              size_t ws_size, hipStream_t stream) {
  const float* x1 = (const float*)d_in[0];
  const float* x2 = (const float*)d_in[1];
  float* out = (float*)d_out;

  uint4* Bfr = (uint4*)d_ws;  // 2*NB*TILES*64 uint4 = 4 MB

  prepack_b<<<(2 * NB * PTS) / 256, 256, 0, stream>>>(x1, x2, Bfr, out);
  dim3 grid(PTS / 128, 2 * NB);  // x = row-group ; y = dir*16 + batch
  chamfer_main<<<grid, 256, 0, stream>>>(x1, x2, Bfr, out);
}

// Round 8
// 123.271 us; speedup vs baseline: 35.1187x; 1.0914x over previous
//
#include <hip/hip_runtime.h>

// Chamfer distance, B=16, N=M=4096, D=3.
// dist(i,j) = n1 + n2 - 2*x1.x2 as ONE bf16 MFMA per 32x32 tile (norms folded
// into padded K slots, hi/lo bf16 split => exact-grade; absmax 0.0 since R1).
// R8: global_load_lds staging. R7's register-streaming died to allocator
// AGPR-parking (VGPR_Count=32 -> MLP~1, 1490 cyc/tile). Now the B-stream
// never touches VGPRs: double-buffered LDS phases (8 tiles = 8 KB) staged by
// global_load_lds width=16 (vmcnt-tracked, drained by __syncthreads), compute
// reads ds_read_b128 (fine-grained lgkmcnt). Also 4x less L2 traffic: one
// global read per block, not per wave. Live set ~110 regs @ (256,3)=168.

typedef __attribute__((ext_vector_type(8))) __bf16 bf16x8;
typedef __attribute__((ext_vector_type(16))) float f32x16;

#define PTS 4096
#define TILES 128   // PTS/32
#define NB 16
#define PH 8        // tiles per phase (8 KB)

__device__ __forceinline__ unsigned f2bf(float f) {
  unsigned u = __float_as_uint(f);
  return (u + 0x7FFFu + ((u >> 16) & 1u)) >> 16;  // RNE bf16 bits
}
__device__ __forceinline__ float bf2f(unsigned s) {
  return __uint_as_float(s << 16);
}
__device__ __forceinline__ unsigned pk(unsigned lo, unsigned hi) {
  return (lo & 0xFFFFu) | (hi << 16);
}
__device__ __forceinline__ void gload_lds16(const void* g, void* l) {
  __builtin_amdgcn_global_load_lds(
      (const __attribute__((address_space(1))) unsigned*)g,
      (__attribute__((address_space(3))) unsigned*)l, 16, 0, 0);
}

// ---- prepack B-side fragments + zero out[] ----
// Bfr slab (d,b): 128 tiles x 1 KB, tile t = [half0: 32x16B][half1: 32x16B].
// B k-vec: w0=[Hx Hy Hz Lx Ly Lz Hx Hy]  w1=[Hz nh nl 1 1 0 0 0], H,L split -2q.
__global__ __launch_bounds__(256) void prepack_b(const float* __restrict__ x1,
                                                 const float* __restrict__ x2,
                                                 uint4* __restrict__ Bfr,
                                                 float* __restrict__ out) {
  const int id = blockIdx.x * 256 + threadIdx.x;  // 2*NB*PTS = 131072
  if (id < NB) out[id] = 0.f;                     // main accumulates into out
  const int d = id >> 16;
  const int b = (id >> 12) & (NB - 1);
  const int j = id & (PTS - 1);
  const float* q = (d ? x1 : x2) + (size_t)(b * PTS + j) * 3;
  const float x = q[0], y = q[1], z = q[2];
  const float sx = -2.f * x, sy = -2.f * y, sz = -2.f * z;
  const unsigned Hx = f2bf(sx), Hy = f2bf(sy), Hz = f2bf(sz);
  const unsigned Lx = f2bf(sx - bf2f(Hx));
  const unsigned Ly = f2bf(sy - bf2f(Hy));
  const unsigned Lz = f2bf(sz - bf2f(Hz));
  const float n = fmaf(x, x, fmaf(y, y, z * z));
  const unsigned nh = f2bf(n), nl = f2bf(n - bf2f(nh));
  const unsigned one = 0x3F80u;
  uint4 w0, w1;
  w0.x = pk(Hx, Hy); w0.y = pk(Hz, Lx); w0.z = pk(Ly, Lz); w0.w = pk(Hx, Hy);
  w1.x = pk(Hz, nh); w1.y = pk(nl, one); w1.z = pk(one, 0u); w1.w = 0u;
  uint4* base = Bfr + ((size_t)((d * NB + b) * TILES + (j >> 5))) * 64 + (j & 31);
  base[0]  = w0;   // half 0
  base[32] = w1;   // half 1
}

// ---- main: 4 waves/block; wave = 1 row-tile (32 rows) x all 128 col-tiles.
// Double-buffered LDS phases of 8 tiles staged via global_load_lds.
__global__ __launch_bounds__(256, 3) void chamfer_main(
    const float* __restrict__ x1, const float* __restrict__ x2,
    const uint4* __restrict__ Bfr, float* __restrict__ out) {
  __shared__ __align__(16) char lds[2][PH * 1024];  // 16 KB

  const int rg = blockIdx.x;           // 32 row-groups of 128 rows
  const int d  = blockIdx.y >> 4;      // direction
  const int b  = blockIdx.y & (NB - 1);

  const int tid  = threadIdx.x;
  const int lane = tid & 63;
  const int half = lane >> 5;          // K-half this lane supplies to MFMA
  const int l31  = lane & 31;
  const int wave = tid >> 6;

  // --- build A fragment from raw points (row tile t0, row = t0*32 + l31) ---
  // A k-vec: w0=[hx hy hz hx hy hz lx ly]  w1=[lz 1 1 nh nl 0 0 0]
  const float* P = d ? x2 : x1;
  const int t0 = rg * 4 + wave;
  bf16x8 af;
  {
    const int r = t0 * 32 + l31;
    const float* p = P + (size_t)(b * PTS + r) * 3;
    const float x = p[0], y = p[1], zc = p[2];
    const unsigned hx = f2bf(x), hy = f2bf(y), hz = f2bf(zc);
    const unsigned lx = f2bf(x - bf2f(hx));
    const unsigned ly = f2bf(y - bf2f(hy));
    const unsigned lz = f2bf(zc - bf2f(hz));
    const float n = fmaf(x, x, fmaf(y, y, zc * zc));
    const unsigned nh = f2bf(n), nl = f2bf(n - bf2f(nh));
    const unsigned one = 0x3F80u;
    uint4 w0, w1;
    w0.x = pk(hx, hy); w0.y = pk(hz, hx); w0.z = pk(hy, hz); w0.w = pk(lx, ly);
    w1.x = pk(lz, one); w1.y = pk(one, nh); w1.z = pk(nl, 0u); w1.w = 0u;
    uint4 w;
    w.x = half ? w1.x : w0.x; w.y = half ? w1.y : w0.y;
    w.z = half ? w1.z : w0.z; w.w = half ? w1.w : w0.w;
    af = *(const bf16x8*)&w;
  }

  f32x16 zero;
#pragma unroll
  for (int e = 0; e < 16; ++e) zero[e] = 0.f;

  float rm[16];
#pragma unroll
  for (int e = 0; e < 16; ++e) rm[e] = 3.0e38f;

  // --- staging geometry: per phase, wave w stages tiles {2w, 2w+1} ---
  const char* slab = (const char*)(Bfr + (size_t)((d * NB + b) * TILES) * 64);
  const int stile = wave * 2;                    // this wave's first stage tile
  const size_t lstride = (size_t)lane * 16;      // lane's 16B within a tile

  // prologue: stage phase 0
#pragma unroll
  for (int k = 0; k < 2; ++k)
    gload_lds16(slab + (stile + k) * 1024 + lstride,
                &lds[0][(stile + k) * 1024]);
  __syncthreads();  // drains vmcnt -> phase 0 resident

  const int foff = (half * 32 + l31) * 16;  // lane's fragment byte offset

  for (int p = 0; p < TILES / PH; ++p) {
    // stage next phase into the other buffer (skipped on last phase)
    if (p + 1 < TILES / PH) {
      const char* g = slab + (p + 1) * PH * 1024;
#pragma unroll
      for (int k = 0; k < 2; ++k)
        gload_lds16(g + (stile + k) * 1024 + lstride,
                    &lds[(p + 1) & 1][(stile + k) * 1024]);
    }
    // compute this phase: 8 ds_read_b128, 8 MFMA, min3-paired folds
    const char* lb = lds[p & 1];
    bf16x8 bf[PH];
#pragma unroll
    for (int t = 0; t < PH; ++t)
      bf[t] = *(const bf16x8*)(lb + t * 1024 + foff);
#pragma unroll
    for (int t = 0; t < PH; t += 2) {
      const f32x16 a0 =
          __builtin_amdgcn_mfma_f32_32x32x16_bf16(af, bf[t], zero, 0, 0, 0);
      const f32x16 a1 =
          __builtin_amdgcn_mfma_f32_32x32x16_bf16(af, bf[t + 1], zero, 0, 0, 0);
#pragma unroll
      for (int e = 0; e < 16; ++e)
        rm[e] = fminf(fminf(a0[e], a1[e]), rm[e]);  // v_min3_f32
    }
    __syncthreads();  // phase consumed; next phase's loads drained
  }

  // --- epilogue: full row mins (butterfly over 32 cols), sum, one atomicAdd.
  // C/D layout: col = lane&31, row_local = (e&3) + 8*(e>>2) + 4*half.
  float ssum = 0.f;
#pragma unroll
  for (int e = 0; e < 16; ++e) {
    float v = rm[e];
    v = fminf(v, __shfl_xor(v, 1));
    v = fminf(v, __shfl_xor(v, 2));
    v = fminf(v, __shfl_xor(v, 4));
    v = fminf(v, __shfl_xor(v, 8));
    v = fminf(v, __shfl_xor(v, 16));
    ssum += v;  // each e is a distinct row of this lane-half
  }
  ssum += __shfl_xor(ssum, 32);  // combine the two 16-row lane halves
  if (lane == 0) atomicAdd(&out[b], ssum * (1.0f / (float)PTS));
}

extern "C" void kernel_launch(void* const* d_in, const int* in_sizes, int n_in,
                              void* d_out, int out_size, void* d_ws,
                              size_t ws_size, hipStream_t stream) {
  const float* x1 = (const float*)d_in[0];
  const float* x2 = (const float*)d_in[1];
  float* out = (float*)d_out;

  uint4* Bfr = (uint4*)d_ws;  // 2*NB*TILES*64 uint4 = 4 MB

  prepack_b<<<(2 * NB * PTS) / 256, 256, 0, stream>>>(x1, x2, Bfr, out);
  dim3 grid(PTS / 128, 2 * NB);  // x = row-group ; y = dir*16 + batch
  chamfer_main<<<grid, 256, 0, stream>>>(x1, x2, Bfr, out);
}